// Round 6
// baseline (1239.245 us; speedup 1.0000x reference)
//
#include <hip/hip_runtime.h>
#include <hip/hip_bf16.h>

#define NROWS 100000
#define EDGES 600000
#define DIM 128

typedef unsigned short u16;

static __device__ __forceinline__ float bf2f(u16 u) {
  union { unsigned u; float f; } c;
  c.u = (unsigned)u << 16;
  return c.f;
}
static __device__ __forceinline__ u16 f2bf(float f) {
  union { float f; unsigned u; } c;
  c.f = f;
  unsigned r = c.u + 0x7fff + ((c.u >> 16) & 1);   // RNE
  return (u16)(r >> 16);
}
static __device__ __forceinline__ long ld_idx(const void* p, long i, int is64) {
  return is64 ? (long)((const long long*)p)[i] : (long)((const int*)p)[i];
}
static __device__ __forceinline__ float ld_f(const int* flags, const void* p, long i) {
  return flags[0] ? ((const float*)p)[i] : bf2f(((const u16*)p)[i]);
}

// flags[0]=fp32 floats; flags[1]=entity i64; flags[2]=edge_index i64; flags[3]=edge_type i64
__global__ __launch_bounds__(256) void detect_kernel(
    const u16* __restrict__ table, const void* __restrict__ entity,
    const void* __restrict__ ei, const void* __restrict__ et,
    int* __restrict__ flags) {
  __shared__ int s_f, s_ei, s_et;
  if (threadIdx.x == 0) { s_f = 0; s_ei = 0; s_et = 0; }
  __syncthreads();
  int cf = 0, cei = 0, cet = 0;
  for (int i = threadIdx.x; i < 65536; i += 256) {
    u16 u = table[i];
    if (((u >> 7) & 0xFF) == 0xFF) cf++;   // finite bf16 never has exp=255
  }
  const int* ei32 = (const int*)ei;
  const int* et32 = (const int*)et;
  for (int i = threadIdx.x; i < 1024; i += 256) {
    if (ei32[2 * i + 1] != 0) cei++;       // i64 high words are all zero
    if (et32[2 * i + 1] != 0) cet++;
  }
  if (cf) atomicAdd(&s_f, cf);
  if (cei) atomicAdd(&s_ei, cei);
  if (cet) atomicAdd(&s_et, cet);
  __syncthreads();
  if (threadIdx.x == 0) {
    flags[0] = (s_f > 0) ? 1 : 0;
    flags[1] = (((const int*)entity)[1] == 0) ? 1 : 0;   // arange word1: i32 -> 1
    flags[2] = (s_ei == 0) ? 1 : 0;
    flags[3] = (s_et == 0) ? 1 : 0;
  }
}

__global__ __launch_bounds__(256) void conv_kernel(const int* __restrict__ flags,
                                                   const void* __restrict__ src,
                                                   float* __restrict__ dst, int n) {
  int i = blockIdx.x * 256 + threadIdx.x;
  if (i < n) dst[i] = ld_f(flags, src, i);
}

// Wcat[k][640] = [basis0..3 | root], fp32
__global__ __launch_bounds__(256) void wcat_kernel(const int* __restrict__ flags,
                                                   const void* __restrict__ basis,
                                                   const void* __restrict__ root,
                                                   float* __restrict__ Wcat) {
  int i = blockIdx.x * 256 + threadIdx.x;
  if (i >= 128 * 640) return;
  int k = i / 640, c = i % 640;
  const void* src;
  long si;
  if (c < 512) { src = basis; si = (long)(c >> 7) * DIM * DIM + k * DIM + (c & 127); }
  else         { src = root;  si = (long)k * DIM + (c - 512); }
  Wcat[i] = ld_f(flags, src, si);
}

// h (fp32, in d_out) = table[entity[row]]
__global__ __launch_bounds__(256) void gather_kernel(const int* __restrict__ flags,
                                                     const void* __restrict__ entity,
                                                     const void* __restrict__ table,
                                                     float* __restrict__ h) {
  int gid = blockIdx.x * 256 + threadIdx.x;      // N*32 threads, 4 elems each
  int row = gid >> 5, c4 = (gid & 31) * 4;
  if (row >= NROWS) return;
  long src = ld_idx(entity, row, flags[1]);
  float4 o;
  if (flags[0]) {
    o = *(const float4*)((const float*)table + src * DIM + c4);
  } else {
    ushort4 a = *(const ushort4*)((const u16*)table + src * DIM + c4);
    o = make_float4(bf2f(a.x), bf2f(a.y), bf2f(a.z), bf2f(a.w));
  }
  *(float4*)(h + (long)row * DIM + c4) = o;
}

// -------- CSR build -------------------------------------------------------------
__global__ __launch_bounds__(256) void hist_kernel(const int* __restrict__ flags,
                                                   const void* __restrict__ ei,
                                                   int* __restrict__ cnt) {
  int e = blockIdx.x * 256 + threadIdx.x;
  if (e < EDGES) atomicAdd(cnt + ld_idx(ei, EDGES + e, flags[2]), 1);
}

__global__ __launch_bounds__(1024) void scan_kernel(const int* __restrict__ cnt,
                                                    int* __restrict__ rowPtr) {
  __shared__ int sh[1024];
  __shared__ int carry;
  if (threadIdx.x == 0) carry = 0;
  __syncthreads();
  for (int base = 0; base < NROWS; base += 1024) {
    int i = base + threadIdx.x;
    int v = (i < NROWS) ? cnt[i] : 0;
    sh[threadIdx.x] = v;
    __syncthreads();
    for (int off = 1; off < 1024; off <<= 1) {
      int t = (threadIdx.x >= off) ? sh[threadIdx.x - off] : 0;
      __syncthreads();
      sh[threadIdx.x] += t;
      __syncthreads();
    }
    int incl = sh[threadIdx.x];
    if (i < NROWS) rowPtr[i] = carry + incl - v;   // exclusive
    __syncthreads();
    if (threadIdx.x == 1023) carry += sh[1023];
    __syncthreads();
  }
  if (threadIdx.x == 0) rowPtr[NROWS] = carry;
}

__global__ __launch_bounds__(256) void scatter_kernel(const int* __restrict__ flags,
                                                      const void* __restrict__ ei,
                                                      const void* __restrict__ et,
                                                      const void* __restrict__ enorm,
                                                      int* __restrict__ cursor,
                                                      int* __restrict__ csr_packed,
                                                      float* __restrict__ csr_norm) {
  int e = blockIdx.x * 256 + threadIdx.x;
  if (e >= EDGES) return;
  int dst = (int)ld_idx(ei, EDGES + e, flags[2]);
  int src = (int)ld_idx(ei, e, flags[2]);
  int t = (int)ld_idx(et, e, flags[3]);
  int pos = atomicAdd(cursor + dst, 1);
  csr_packed[pos] = src | (t << 17);   // src < 2^17, t < 1000
  csr_norm[pos] = ld_f(flags, enorm, e);
}

// -------- fp32 GEMM. by<nYtiles: Y tiles (Wcat cols 0..511, bf16 out).
// by>=nYtiles: root tiles (cols 512..639) -> acc (+bias), fp32 or bf16.
__global__ __launch_bounds__(256) void gemm_kernel(
    const float* __restrict__ h, const float* __restrict__ Wcat,
    const float* __restrict__ bias, u16* __restrict__ Y,
    void* __restrict__ acc, int accF32, int rowBase, int rowEnd, int nYtiles) {
  __shared__ float As[64][132];   // [k][m]
  __shared__ float Ws[64][68];    // [k][n]
  int by = blockIdx.y;
  int isRoot = (by >= nYtiles);
  int gcol = isRoot ? (512 + (by - nYtiles) * 64) : (by * 64);
  long m0 = rowBase + (long)blockIdx.x * 128;
  int tx = threadIdx.x & 15, ty = threadIdx.x >> 4;
  float av[8][4] = {};

  for (int k0 = 0; k0 < 128; k0 += 64) {
#pragma unroll
    for (int it = 0; it < 8; ++it) {              // stage A (transpose)
      int lin = threadIdx.x + it * 256;           // 0..2047
      int row = lin >> 4, c4 = (lin & 15) * 4;
      long grow = m0 + row;
      float4 v = make_float4(0.f, 0.f, 0.f, 0.f);
      if (grow < rowEnd) v = *(const float4*)&h[grow * DIM + k0 + c4];
      As[c4 + 0][row] = v.x;
      As[c4 + 1][row] = v.y;
      As[c4 + 2][row] = v.z;
      As[c4 + 3][row] = v.w;
    }
#pragma unroll
    for (int it = 0; it < 4; ++it) {              // stage W
      int lin = threadIdx.x + it * 256;
      int k = lin >> 4, n4 = lin & 15;
      *(float4*)&Ws[k][n4 * 4] = *(const float4*)&Wcat[(long)(k0 + k) * 640 + gcol + n4 * 4];
    }
    __syncthreads();
#pragma unroll
    for (int k = 0; k < 64; ++k) {
      float a[8], b[4];
      *(float4*)&a[0] = *(const float4*)&As[k][ty * 8];
      *(float4*)&a[4] = *(const float4*)&As[k][ty * 8 + 4];
      *(float4*)&b[0] = *(const float4*)&Ws[k][tx * 4];
#pragma unroll
      for (int i = 0; i < 8; ++i)
#pragma unroll
        for (int j = 0; j < 4; ++j) av[i][j] = fmaf(a[i], b[j], av[i][j]);
    }
    __syncthreads();
  }

#pragma unroll
  for (int i = 0; i < 8; ++i) {
    long row = m0 + ty * 8 + i;
    if (row >= rowEnd) continue;
    if (isRoot) {
      int c = gcol - 512 + tx * 4;
      float o0 = av[i][0] + bias[c], o1 = av[i][1] + bias[c + 1];
      float o2 = av[i][2] + bias[c + 2], o3 = av[i][3] + bias[c + 3];
      if (accF32) {
        *(float4*)&((float*)acc)[row * DIM + c] = make_float4(o0, o1, o2, o3);
      } else {
        *(ushort4*)&((u16*)acc)[row * DIM + c] =
            make_ushort4(f2bf(o0), f2bf(o1), f2bf(o2), f2bf(o3));
      }
    } else {
      *(ushort4*)&Y[(row - rowBase) * 512 + gcol + tx * 4] =
          make_ushort4(f2bf(av[i][0]), f2bf(av[i][1]), f2bf(av[i][2]), f2bf(av[i][3]));
    }
  }
}

// -------- CSR aggregation, one wave/node, src filtered to [c0,c1) ---------------
// finalMode 0: acc += msg/deg | 1: out = relu(acc+msg/deg) fp32 | 2: out fp32
__global__ __launch_bounds__(256) void agg_kernel(
    const int* __restrict__ rowPtr, const int* __restrict__ csr_packed,
    const float* __restrict__ csr_norm, const float* __restrict__ att_f,
    const u16* __restrict__ Y, int c0, int c1,
    void* __restrict__ acc, int accF32, int finalMode, float* __restrict__ outp) {
  int wid = (blockIdx.x * 256 + threadIdx.x) >> 6;
  int lane = threadIdx.x & 63;
  if (wid >= NROWS) return;
  int beg = rowPtr[wid], end = rowPtr[wid + 1];
  int d = lane * 2;
  float m0 = 0.f, m1 = 0.f;
  for (int e = beg; e < end; ++e) {
    int pk = csr_packed[e];
    int src = pk & 0x1FFFF;
    if ((unsigned)(src - c0) >= (unsigned)(c1 - c0)) continue;
    int t = pk >> 17;
    float nrm = csr_norm[e];
    const u16* y = Y + (long)(src - c0) * 512;
    float w[4];
#pragma unroll
    for (int b = 0; b < 4; ++b) w[b] = att_f[t * 4 + b] * nrm;
#pragma unroll
    for (int b = 0; b < 4; ++b) {
      unsigned v = *(const unsigned*)(y + b * DIM + d);
      m0 += w[b] * bf2f((u16)(v & 0xffffu));
      m1 += w[b] * bf2f((u16)(v >> 16));
    }
  }
  float invd = 1.0f / fmaxf((float)(end - beg), 1.0f);
  m0 *= invd; m1 *= invd;
  long o = (long)wid * DIM + d;
  if (finalMode == 0) {
    if (accF32) {
      ((float*)acc)[o] += m0;
      ((float*)acc)[o + 1] += m1;
    } else {
      u16* a = (u16*)acc;
      a[o] = f2bf(bf2f(a[o]) + m0);
      a[o + 1] = f2bf(bf2f(a[o + 1]) + m1);
    }
  } else {
    float a0, a1;
    if (accF32) { a0 = ((float*)acc)[o]; a1 = ((float*)acc)[o + 1]; }
    else        { a0 = bf2f(((u16*)acc)[o]); a1 = bf2f(((u16*)acc)[o + 1]); }
    float v0 = a0 + m0, v1 = a1 + m1;
    if (finalMode == 1) { v0 = fmaxf(v0, 0.f); v1 = fmaxf(v1, 0.f); }
    outp[o] = v0;
    outp[o + 1] = v1;
  }
}

// rel_emb passthrough as fp32
__global__ __launch_bounds__(256) void relout_kernel(const int* __restrict__ flags,
                                                     const void* __restrict__ rel,
                                                     float* __restrict__ out) {
  int i = blockIdx.x * 256 + threadIdx.x;
  if (i < 500 * DIM) out[i] = ld_f(flags, rel, i);
}

static size_t alignup(size_t x) { return (x + 255) & ~(size_t)255; }

extern "C" void kernel_launch(void* const* d_in, const int* in_sizes, int n_in,
                              void* d_out, int out_size, void* d_ws, size_t ws_size,
                              hipStream_t stream) {
  // ---- input mapping, verified against expected element counts ----
  static const long exp_sz[15] = {100000, 1200000, 600000, 600000, 250000,
                                  12800000, 64000, 65536, 4000, 16384, 128,
                                  65536, 4000, 16384, 128};
  int map[15];
  bool posOK = (n_in >= 15);
  for (int i = 0; posOK && i < 15; ++i) posOK = (in_sizes[i] == exp_sz[i]);
  if (posOK) {
    for (int i = 0; i < 15; ++i) map[i] = i;
  } else {
    bool used[64] = {};
    for (int i = 0; i < 15; ++i) {
      map[i] = -1;
      for (int j = 0; j < n_in && j < 64; ++j)
        if (!used[j] && in_sizes[j] == exp_sz[i]) { map[i] = j; used[j] = true; break; }
      if (map[i] < 0) map[i] = (i < n_in) ? i : 0;
    }
  }
  const void* entity = d_in[map[0]];
  const void* edge_index = d_in[map[1]];
  const void* edge_type = d_in[map[2]];
  const void* edge_norm = d_in[map[3]];
  const void* table = d_in[map[5]];
  const void* rel_emb = d_in[map[6]];
  const void* basis[2] = {d_in[map[7]], d_in[map[11]]};
  const void* att[2] = {d_in[map[8]], d_in[map[12]]};
  const void* root[2] = {d_in[map[9]], d_in[map[13]]};
  const void* bias[2] = {d_in[map[10]], d_in[map[14]]};

  // ---- fixed ws layout (~6.7 MB) ----
  char* ws = (char*)d_ws;
  size_t off = 0;
  auto grab = [&](size_t bytes) { size_t o = off; off = alignup(off + bytes); return o; };
  int* flags = (int*)(ws + grab(16));
  float* att_f[2] = {(float*)(ws + grab(4000 * 4)), (float*)(ws + grab(4000 * 4))};
  float* bias_f[2] = {(float*)(ws + grab(DIM * 4)), (float*)(ws + grab(DIM * 4))};
  float* Wcat[2] = {(float*)(ws + grab(128 * 640 * 4)), (float*)(ws + grab(128 * 640 * 4))};
  int* cnt = (int*)(ws + grab((size_t)NROWS * 4));
  int* cursor = (int*)(ws + grab((size_t)NROWS * 4));
  int* rowPtr = (int*)(ws + grab((size_t)(NROWS + 1) * 4));
  int* csr_packed = (int*)(ws + grab((size_t)EDGES * 4));
  float* csr_norm = (float*)(ws + grab((size_t)EDGES * 4));
  size_t fixedB = off;

  // ---- pick (node-chunks NC, acc precision) that fits ws_size ----
  const size_t accF32B = (size_t)NROWS * DIM * 4, accBF16B = (size_t)NROWS * DIM * 2;
  static const int ncOrd[10] = {1, 2, 4, 8, 16, 1, 2, 4, 8, 16};
  static const int f32Ord[10] = {1, 1, 1, 1, 1, 0, 0, 0, 0, 0};
  int NC = 16, accF32 = 0;
  for (int i = 0; i < 10; ++i) {
    int nc = ncOrd[i];
    size_t r = (NROWS + nc - 1) / nc;
    size_t need = fixedB + (f32Ord[i] ? accF32B : accBF16B) + r * 512 * 2;
    if (need <= ws_size) { NC = nc; accF32 = f32Ord[i]; break; }
  }
  void* acc = (void*)(ws + grab(accF32 ? accF32B : accBF16B));
  const int rpc = (NROWS + NC - 1) / NC;
  u16* Y = (u16*)(ws + grab((size_t)rpc * 512 * 2));
  float* h = (float*)d_out;   // fp32 node features live in the output region

  // ---- prep ----
  detect_kernel<<<1, 256, 0, stream>>>((const u16*)table, entity, edge_index,
                                       edge_type, flags);
  for (int l = 0; l < 2; ++l) {
    wcat_kernel<<<320, 256, 0, stream>>>(flags, basis[l], root[l], Wcat[l]);
    conv_kernel<<<16, 256, 0, stream>>>(flags, att[l], att_f[l], 4000);
    conv_kernel<<<1, 256, 0, stream>>>(flags, bias[l], bias_f[l], DIM);
  }
  gather_kernel<<<(NROWS * 32 + 255) / 256, 256, 0, stream>>>(flags, entity, table, h);
  hipMemsetAsync(cnt, 0, (size_t)NROWS * 4, stream);
  hist_kernel<<<(EDGES + 255) / 256, 256, 0, stream>>>(flags, edge_index, cnt);
  scan_kernel<<<1, 1024, 0, stream>>>(cnt, rowPtr);
  hipMemcpyAsync(cursor, rowPtr, (size_t)NROWS * 4, hipMemcpyDeviceToDevice, stream);
  scatter_kernel<<<(EDGES + 255) / 256, 256, 0, stream>>>(
      flags, edge_index, edge_type, edge_norm, cursor, csr_packed, csr_norm);

  // ---- two RGCN layers ----
  const int aggBlocks = (NROWS * 64) / 256;           // 25000
  const int rootMt = (NROWS + 127) / 128;             // 782
  for (int l = 0; l < 2; ++l) {
    // acc = h @ root + bias (all rows); nYtiles=0 -> both by tiles are root tiles
    gemm_kernel<<<dim3(rootMt, 2), 256, 0, stream>>>(
        h, Wcat[l], bias_f[l], Y, acc, accF32, 0, NROWS, 0);
    for (int c = 0; c < NC; ++c) {
      int c0 = c * rpc, c1 = (c0 + rpc < NROWS) ? c0 + rpc : NROWS;
      int mt = (c1 - c0 + 127) / 128;
      gemm_kernel<<<dim3(mt, 8), 256, 0, stream>>>(
          h, Wcat[l], bias_f[l], Y, acc, accF32, c0, c1, 8);
      int fm = (c == NC - 1) ? (l == 0 ? 1 : 2) : 0;
      agg_kernel<<<aggBlocks, 256, 0, stream>>>(
          rowPtr, csr_packed, csr_norm, att_f[l], Y, c0, c1, acc, accF32, fm, h);
    }
  }

  relout_kernel<<<250, 256, 0, stream>>>(flags, rel_emb, (float*)d_out + (size_t)NROWS * DIM);
}

// Round 7
// 888.743 us; speedup vs baseline: 1.3944x; 1.3944x over previous
//
#include <hip/hip_runtime.h>
#include <hip/hip_bf16.h>

#define NROWS 100000
#define EDGES 600000
#define DIM 128

typedef unsigned short u16;
typedef __attribute__((ext_vector_type(8))) short v8s;   // 8 bf16 (4 VGPRs)
typedef __attribute__((ext_vector_type(4))) float v4f;

static __device__ __forceinline__ float bf2f(u16 u) {
  union { unsigned u; float f; } c;
  c.u = (unsigned)u << 16;
  return c.f;
}
static __device__ __forceinline__ u16 f2bf(float f) {
  union { float f; unsigned u; } c;
  c.f = f;
  unsigned r = c.u + 0x7fff + ((c.u >> 16) & 1);   // RNE
  return (u16)(r >> 16);
}
static __device__ __forceinline__ long ld_idx(const void* p, long i, int is64) {
  return is64 ? (long)((const long long*)p)[i] : (long)((const int*)p)[i];
}
static __device__ __forceinline__ float ld_f(const int* flags, const void* p, long i) {
  return flags[0] ? ((const float*)p)[i] : bf2f(((const u16*)p)[i]);
}

// flags[0]=fp32 floats; flags[1]=entity i64; flags[2]=edge_index i64; flags[3]=edge_type i64
__global__ __launch_bounds__(256) void detect_kernel(
    const u16* __restrict__ table, const void* __restrict__ entity,
    const void* __restrict__ ei, const void* __restrict__ et,
    int* __restrict__ flags) {
  __shared__ int s_f, s_ei, s_et;
  if (threadIdx.x == 0) { s_f = 0; s_ei = 0; s_et = 0; }
  __syncthreads();
  int cf = 0, cei = 0, cet = 0;
  for (int i = threadIdx.x; i < 65536; i += 256) {
    u16 u = table[i];
    if (((u >> 7) & 0xFF) == 0xFF) cf++;
  }
  const int* ei32 = (const int*)ei;
  const int* et32 = (const int*)et;
  for (int i = threadIdx.x; i < 1024; i += 256) {
    if (ei32[2 * i + 1] != 0) cei++;
    if (et32[2 * i + 1] != 0) cet++;
  }
  if (cf) atomicAdd(&s_f, cf);
  if (cei) atomicAdd(&s_ei, cei);
  if (cet) atomicAdd(&s_et, cet);
  __syncthreads();
  if (threadIdx.x == 0) {
    flags[0] = (s_f > 0) ? 1 : 0;
    flags[1] = (((const int*)entity)[1] == 0) ? 1 : 0;
    flags[2] = (s_ei == 0) ? 1 : 0;
    flags[3] = (s_et == 0) ? 1 : 0;
  }
}

__global__ __launch_bounds__(256) void conv_kernel(const int* __restrict__ flags,
                                                   const void* __restrict__ src,
                                                   float* __restrict__ dst, int n) {
  int i = blockIdx.x * 256 + threadIdx.x;
  if (i < n) dst[i] = ld_f(flags, src, i);
}

// Wcat[k][640] = [basis0..3 | root], fp32 (root slice feeds the fp32 root GEMM)
__global__ __launch_bounds__(256) void wcat_kernel(const int* __restrict__ flags,
                                                   const void* __restrict__ basis,
                                                   const void* __restrict__ root,
                                                   float* __restrict__ Wcat) {
  int i = blockIdx.x * 256 + threadIdx.x;
  if (i >= 128 * 640) return;
  int k = i / 640, c = i % 640;
  const void* src;
  long si;
  if (c < 512) { src = basis; si = (long)(c >> 7) * DIM * DIM + k * DIM + (c & 127); }
  else         { src = root;  si = (long)k * DIM + (c - 512); }
  Wcat[i] = ld_f(flags, src, si);
}

// Wt[512][128] bf16 = transposed bases: Wt[b*128+c][k] = basis[b][k][c]
__global__ __launch_bounds__(256) void wtbf_kernel(const int* __restrict__ flags,
                                                   const void* __restrict__ basis,
                                                   u16* __restrict__ Wt) {
  int i = blockIdx.x * 256 + threadIdx.x;
  if (i >= 512 * 128) return;
  int n = i >> 7, k = i & 127;
  int b = n >> 7, c = n & 127;
  Wt[i] = f2bf(ld_f(flags, basis, (long)b * DIM * DIM + (long)k * DIM + c));
}

// h fp32 (d_out) + hbf bf16 (ws) = table[entity[row]]
__global__ __launch_bounds__(256) void gather_kernel(const int* __restrict__ flags,
                                                     const void* __restrict__ entity,
                                                     const void* __restrict__ table,
                                                     float* __restrict__ h,
                                                     u16* __restrict__ hbf) {
  int gid = blockIdx.x * 256 + threadIdx.x;      // N*32 threads, 4 elems each
  int row = gid >> 5, c4 = (gid & 31) * 4;
  if (row >= NROWS) return;
  long src = ld_idx(entity, row, flags[1]);
  float4 o;
  if (flags[0]) {
    o = *(const float4*)((const float*)table + src * DIM + c4);
  } else {
    ushort4 a = *(const ushort4*)((const u16*)table + src * DIM + c4);
    o = make_float4(bf2f(a.x), bf2f(a.y), bf2f(a.z), bf2f(a.w));
  }
  *(float4*)(h + (long)row * DIM + c4) = o;
  *(ushort4*)(hbf + (long)row * DIM + c4) =
      make_ushort4(f2bf(o.x), f2bf(o.y), f2bf(o.z), f2bf(o.w));
}

// -------- CSR build -------------------------------------------------------------
__global__ __launch_bounds__(256) void hist_kernel(const int* __restrict__ flags,
                                                   const void* __restrict__ ei,
                                                   int* __restrict__ cnt) {
  int e = blockIdx.x * 256 + threadIdx.x;
  if (e < EDGES) atomicAdd(cnt + ld_idx(ei, EDGES + e, flags[2]), 1);
}

__global__ __launch_bounds__(1024) void scan_kernel(const int* __restrict__ cnt,
                                                    int* __restrict__ rowPtr) {
  __shared__ int sh[1024];
  __shared__ int carry;
  if (threadIdx.x == 0) carry = 0;
  __syncthreads();
  for (int base = 0; base < NROWS; base += 1024) {
    int i = base + threadIdx.x;
    int v = (i < NROWS) ? cnt[i] : 0;
    sh[threadIdx.x] = v;
    __syncthreads();
    for (int off = 1; off < 1024; off <<= 1) {
      int t = (threadIdx.x >= off) ? sh[threadIdx.x - off] : 0;
      __syncthreads();
      sh[threadIdx.x] += t;
      __syncthreads();
    }
    int incl = sh[threadIdx.x];
    if (i < NROWS) rowPtr[i] = carry + incl - v;
    __syncthreads();
    if (threadIdx.x == 1023) carry += sh[1023];
    __syncthreads();
  }
  if (threadIdx.x == 0) rowPtr[NROWS] = carry;
}

__global__ __launch_bounds__(256) void scatter_kernel(const int* __restrict__ flags,
                                                      const void* __restrict__ ei,
                                                      const void* __restrict__ et,
                                                      const void* __restrict__ enorm,
                                                      int* __restrict__ cursor,
                                                      int* __restrict__ csr_packed,
                                                      float* __restrict__ csr_norm) {
  int e = blockIdx.x * 256 + threadIdx.x;
  if (e >= EDGES) return;
  int dst = (int)ld_idx(ei, EDGES + e, flags[2]);
  int src = (int)ld_idx(ei, e, flags[2]);
  int t = (int)ld_idx(et, e, flags[3]);
  int pos = atomicAdd(cursor + dst, 1);
  csr_packed[pos] = src | (t << 17);
  csr_norm[pos] = ld_f(flags, enorm, e);
}

// -------- fp32 GEMM (root path only: by>=nYtiles=0): acc = h@root + bias --------
__global__ __launch_bounds__(256) void gemm_kernel(
    const float* __restrict__ h, const float* __restrict__ Wcat,
    const float* __restrict__ bias, u16* __restrict__ Y,
    void* __restrict__ acc, int accF32, int rowBase, int rowEnd, int nYtiles) {
  __shared__ float As[64][132];
  __shared__ float Ws[64][68];
  int by = blockIdx.y;
  int isRoot = (by >= nYtiles);
  int gcol = isRoot ? (512 + (by - nYtiles) * 64) : (by * 64);
  long m0 = rowBase + (long)blockIdx.x * 128;
  int tx = threadIdx.x & 15, ty = threadIdx.x >> 4;
  float av[8][4] = {};

  for (int k0 = 0; k0 < 128; k0 += 64) {
#pragma unroll
    for (int it = 0; it < 8; ++it) {
      int lin = threadIdx.x + it * 256;
      int row = lin >> 4, c4 = (lin & 15) * 4;
      long grow = m0 + row;
      float4 v = make_float4(0.f, 0.f, 0.f, 0.f);
      if (grow < rowEnd) v = *(const float4*)&h[grow * DIM + k0 + c4];
      As[c4 + 0][row] = v.x;
      As[c4 + 1][row] = v.y;
      As[c4 + 2][row] = v.z;
      As[c4 + 3][row] = v.w;
    }
#pragma unroll
    for (int it = 0; it < 4; ++it) {
      int lin = threadIdx.x + it * 256;
      int k = lin >> 4, n4 = lin & 15;
      *(float4*)&Ws[k][n4 * 4] = *(const float4*)&Wcat[(long)(k0 + k) * 640 + gcol + n4 * 4];
    }
    __syncthreads();
#pragma unroll
    for (int k = 0; k < 64; ++k) {
      float a[8], b[4];
      *(float4*)&a[0] = *(const float4*)&As[k][ty * 8];
      *(float4*)&a[4] = *(const float4*)&As[k][ty * 8 + 4];
      *(float4*)&b[0] = *(const float4*)&Ws[k][tx * 4];
#pragma unroll
      for (int i = 0; i < 8; ++i)
#pragma unroll
        for (int j = 0; j < 4; ++j) av[i][j] = fmaf(a[i], b[j], av[i][j]);
    }
    __syncthreads();
  }

#pragma unroll
  for (int i = 0; i < 8; ++i) {
    long row = m0 + ty * 8 + i;
    if (row >= rowEnd) continue;
    if (isRoot) {
      int c = gcol - 512 + tx * 4;
      float o0 = av[i][0] + bias[c], o1 = av[i][1] + bias[c + 1];
      float o2 = av[i][2] + bias[c + 2], o3 = av[i][3] + bias[c + 3];
      if (accF32) {
        *(float4*)&((float*)acc)[row * DIM + c] = make_float4(o0, o1, o2, o3);
      } else {
        *(ushort4*)&((u16*)acc)[row * DIM + c] =
            make_ushort4(f2bf(o0), f2bf(o1), f2bf(o2), f2bf(o3));
      }
    } else {
      *(ushort4*)&Y[(row - rowBase) * 512 + gcol + tx * 4] =
          make_ushort4(f2bf(av[i][0]), f2bf(av[i][1]), f2bf(av[i][2]), f2bf(av[i][3]));
    }
  }
}

// -------- MFMA bf16 GEMM: Y[chunk rows][512] = hbf @ bases ----------------------
// block 256 thr (4 waves), tile M=64 x N=128; grid (ceil(rows/64), 4)
__global__ __launch_bounds__(256) void mgemm_kernel(
    const u16* __restrict__ hbf, const u16* __restrict__ Wt,   // Wt[512][128] bf16
    u16* __restrict__ Y, int rowBase, int rowEnd) {
  __shared__ u16 Wl[128 * 136];    // [n_local][k], stride 136 (2-way conflicts only)
  int nb = blockIdx.y * 128;       // global n base (0..384)
#pragma unroll
  for (int it = 0; it < 8; ++it) {
    int idx = threadIdx.x + it * 256;        // 0..2047
    int n = idx >> 4, kk = (idx & 15) * 8;
    *(int4*)&Wl[n * 136 + kk] = *(const int4*)&Wt[(long)(nb + n) * 128 + kk];
  }
  __syncthreads();

  int wave = threadIdx.x >> 6, lane = threadIdx.x & 63;
  int quad = lane >> 4, l16 = lane & 15;
  long arow = rowBase + (long)blockIdx.x * 64 + wave * 16 + l16;
  bool rv = arow < rowEnd;

  v4f acc[8];
#pragma unroll
  for (int nt = 0; nt < 8; ++nt) acc[nt] = (v4f){0.f, 0.f, 0.f, 0.f};

#pragma unroll
  for (int ks = 0; ks < 4; ++ks) {
    int k0 = ks * 32;
    v8s a = {0, 0, 0, 0, 0, 0, 0, 0};
    if (rv) a = *(const v8s*)&hbf[arow * DIM + k0 + quad * 8];
#pragma unroll
    for (int nt = 0; nt < 8; ++nt) {
      v8s b = *(const v8s*)&Wl[(nt * 16 + l16) * 136 + k0 + quad * 8];
      acc[nt] = __builtin_amdgcn_mfma_f32_16x16x32_bf16(a, b, acc[nt], 0, 0, 0);
    }
  }

  // D: col = lane&15, row = quad*4 + r  [verified m89/m91]
  long lrow0 = (long)blockIdx.x * 64 + wave * 16 + quad * 4;   // chunk-local
#pragma unroll
  for (int nt = 0; nt < 8; ++nt) {
#pragma unroll
    for (int r = 0; r < 4; ++r) {
      long lrow = lrow0 + r;
      if (rowBase + lrow < rowEnd)
        Y[lrow * 512 + nb + nt * 16 + l16] = f2bf(acc[nt][r]);
    }
  }
}

// -------- CSR aggregation, one wave/node, src filtered to [c0,c1) ---------------
// finalMode 0: acc += msg/deg | 1: h fp32 + hbf bf16 = relu(acc+msg/deg) | 2: out fp32
__global__ __launch_bounds__(256) void agg_kernel(
    const int* __restrict__ rowPtr, const int* __restrict__ csr_packed,
    const float* __restrict__ csr_norm, const float* __restrict__ att_f,
    const u16* __restrict__ Y, int c0, int c1,
    void* __restrict__ acc, int accF32, int finalMode,
    float* __restrict__ outp, u16* __restrict__ hbfOut) {
  int wid = (blockIdx.x * 256 + threadIdx.x) >> 6;
  int lane = threadIdx.x & 63;
  if (wid >= NROWS) return;
  int beg = rowPtr[wid], end = rowPtr[wid + 1];
  int d = lane * 2;
  float m0 = 0.f, m1 = 0.f;
  for (int e = beg; e < end; ++e) {
    int pk = csr_packed[e];
    int src = pk & 0x1FFFF;
    if ((unsigned)(src - c0) >= (unsigned)(c1 - c0)) continue;
    int t = pk >> 17;
    float nrm = csr_norm[e];
    const u16* y = Y + (long)(src - c0) * 512;
    float w[4];
#pragma unroll
    for (int b = 0; b < 4; ++b) w[b] = att_f[t * 4 + b] * nrm;
#pragma unroll
    for (int b = 0; b < 4; ++b) {
      unsigned v = *(const unsigned*)(y + b * DIM + d);
      m0 += w[b] * bf2f((u16)(v & 0xffffu));
      m1 += w[b] * bf2f((u16)(v >> 16));
    }
  }
  float invd = 1.0f / fmaxf((float)(end - beg), 1.0f);
  m0 *= invd; m1 *= invd;
  long o = (long)wid * DIM + d;
  if (finalMode == 0) {
    if (accF32) {
      ((float*)acc)[o] += m0;
      ((float*)acc)[o + 1] += m1;
    } else {
      u16* a = (u16*)acc;
      a[o] = f2bf(bf2f(a[o]) + m0);
      a[o + 1] = f2bf(bf2f(a[o + 1]) + m1);
    }
  } else {
    float a0, a1;
    if (accF32) { a0 = ((float*)acc)[o]; a1 = ((float*)acc)[o + 1]; }
    else        { a0 = bf2f(((u16*)acc)[o]); a1 = bf2f(((u16*)acc)[o + 1]); }
    float v0 = a0 + m0, v1 = a1 + m1;
    if (finalMode == 1) {
      v0 = fmaxf(v0, 0.f); v1 = fmaxf(v1, 0.f);
      outp[o] = v0;
      outp[o + 1] = v1;
      hbfOut[o] = f2bf(v0);
      hbfOut[o + 1] = f2bf(v1);
    } else {
      outp[o] = v0;
      outp[o + 1] = v1;
    }
  }
}

__global__ __launch_bounds__(256) void relout_kernel(const int* __restrict__ flags,
                                                     const void* __restrict__ rel,
                                                     float* __restrict__ out) {
  int i = blockIdx.x * 256 + threadIdx.x;
  if (i < 500 * DIM) out[i] = ld_f(flags, rel, i);
}

static size_t alignup(size_t x) { return (x + 255) & ~(size_t)255; }

extern "C" void kernel_launch(void* const* d_in, const int* in_sizes, int n_in,
                              void* d_out, int out_size, void* d_ws, size_t ws_size,
                              hipStream_t stream) {
  static const long exp_sz[15] = {100000, 1200000, 600000, 600000, 250000,
                                  12800000, 64000, 65536, 4000, 16384, 128,
                                  65536, 4000, 16384, 128};
  int map[15];
  bool posOK = (n_in >= 15);
  for (int i = 0; posOK && i < 15; ++i) posOK = (in_sizes[i] == exp_sz[i]);
  if (posOK) {
    for (int i = 0; i < 15; ++i) map[i] = i;
  } else {
    bool used[64] = {};
    for (int i = 0; i < 15; ++i) {
      map[i] = -1;
      for (int j = 0; j < n_in && j < 64; ++j)
        if (!used[j] && in_sizes[j] == exp_sz[i]) { map[i] = j; used[j] = true; break; }
      if (map[i] < 0) map[i] = (i < n_in) ? i : 0;
    }
  }
  const void* entity = d_in[map[0]];
  const void* edge_index = d_in[map[1]];
  const void* edge_type = d_in[map[2]];
  const void* edge_norm = d_in[map[3]];
  const void* table = d_in[map[5]];
  const void* rel_emb = d_in[map[6]];
  const void* basis[2] = {d_in[map[7]], d_in[map[11]]};
  const void* att[2] = {d_in[map[8]], d_in[map[12]]};
  const void* root[2] = {d_in[map[9]], d_in[map[13]]};
  const void* bias[2] = {d_in[map[10]], d_in[map[14]]};

  // ---- fixed ws layout (~32.5 MB incl. hbf) ----
  char* ws = (char*)d_ws;
  size_t off = 0;
  auto grab = [&](size_t bytes) { size_t o = off; off = alignup(off + bytes); return o; };
  int* flags = (int*)(ws + grab(16));
  float* att_f[2] = {(float*)(ws + grab(4000 * 4)), (float*)(ws + grab(4000 * 4))};
  float* bias_f[2] = {(float*)(ws + grab(DIM * 4)), (float*)(ws + grab(DIM * 4))};
  float* Wcat[2] = {(float*)(ws + grab(128 * 640 * 4)), (float*)(ws + grab(128 * 640 * 4))};
  u16* Wt[2] = {(u16*)(ws + grab(512 * 128 * 2)), (u16*)(ws + grab(512 * 128 * 2))};
  int* cnt = (int*)(ws + grab((size_t)NROWS * 4));
  int* cursor = (int*)(ws + grab((size_t)NROWS * 4));
  int* rowPtr = (int*)(ws + grab((size_t)(NROWS + 1) * 4));
  int* csr_packed = (int*)(ws + grab((size_t)EDGES * 4));
  float* csr_norm = (float*)(ws + grab((size_t)EDGES * 4));
  u16* hbf = (u16*)(ws + grab((size_t)NROWS * DIM * 2));
  size_t fixedB = off;

  // ---- pick (node-chunks NC, acc precision) that fits ws_size ----
  const size_t accF32B = (size_t)NROWS * DIM * 4, accBF16B = (size_t)NROWS * DIM * 2;
  static const int ncOrd[10] = {1, 2, 4, 8, 16, 1, 2, 4, 8, 16};
  static const int f32Ord[10] = {1, 1, 1, 1, 1, 0, 0, 0, 0, 0};
  int NC = 16, accF32 = 0;
  for (int i = 0; i < 10; ++i) {
    int nc = ncOrd[i];
    size_t r = (NROWS + nc - 1) / nc;
    size_t need = fixedB + (f32Ord[i] ? accF32B : accBF16B) + r * 512 * 2;
    if (need <= ws_size) { NC = nc; accF32 = f32Ord[i]; break; }
  }
  void* acc = (void*)(ws + grab(accF32 ? accF32B : accBF16B));
  const int rpc = (NROWS + NC - 1) / NC;
  u16* Y = (u16*)(ws + grab((size_t)rpc * 512 * 2));
  float* h = (float*)d_out;   // fp32 node features live in the output region

  // ---- prep ----
  detect_kernel<<<1, 256, 0, stream>>>((const u16*)table, entity, edge_index,
                                       edge_type, flags);
  for (int l = 0; l < 2; ++l) {
    wcat_kernel<<<320, 256, 0, stream>>>(flags, basis[l], root[l], Wcat[l]);
    wtbf_kernel<<<256, 256, 0, stream>>>(flags, basis[l], Wt[l]);
    conv_kernel<<<16, 256, 0, stream>>>(flags, att[l], att_f[l], 4000);
    conv_kernel<<<1, 256, 0, stream>>>(flags, bias[l], bias_f[l], DIM);
  }
  gather_kernel<<<(NROWS * 32 + 255) / 256, 256, 0, stream>>>(flags, entity, table, h, hbf);
  hipMemsetAsync(cnt, 0, (size_t)NROWS * 4, stream);
  hist_kernel<<<(EDGES + 255) / 256, 256, 0, stream>>>(flags, edge_index, cnt);
  scan_kernel<<<1, 1024, 0, stream>>>(cnt, rowPtr);
  hipMemcpyAsync(cursor, rowPtr, (size_t)NROWS * 4, hipMemcpyDeviceToDevice, stream);
  scatter_kernel<<<(EDGES + 255) / 256, 256, 0, stream>>>(
      flags, edge_index, edge_type, edge_norm, cursor, csr_packed, csr_norm);

  // ---- two RGCN layers ----
  const int aggBlocks = (NROWS * 64) / 256;           // 25000
  const int rootMt = (NROWS + 127) / 128;             // 782
  for (int l = 0; l < 2; ++l) {
    // acc = h @ root + bias (fp32 path, protects output precision)
    gemm_kernel<<<dim3(rootMt, 2), 256, 0, stream>>>(
        h, Wcat[l], bias_f[l], Y, acc, accF32, 0, NROWS, 0);
    for (int c = 0; c < NC; ++c) {
      int c0 = c * rpc, c1 = (c0 + rpc < NROWS) ? c0 + rpc : NROWS;
      int mt = (c1 - c0 + 63) / 64;
      mgemm_kernel<<<dim3(mt, 4), 256, 0, stream>>>(hbf, Wt[l], Y, c0, c1);
      int fm = (c == NC - 1) ? (l == 0 ? 1 : 2) : 0;
      agg_kernel<<<aggBlocks, 256, 0, stream>>>(
          rowPtr, csr_packed, csr_norm, att_f[l], Y, c0, c1, acc, accF32, fm, h, hbf);
    }
  }

  relout_kernel<<<250, 256, 0, stream>>>(flags, rel_emb, (float*)d_out + (size_t)NROWS * DIM);
}

// Round 8
// 713.413 us; speedup vs baseline: 1.7371x; 1.2458x over previous
//
#include <hip/hip_runtime.h>
#include <hip/hip_bf16.h>

#define NROWS 100000
#define EDGES 600000
#define DIM 128
#define SCAN_B 391   // ceil(100000/256)

typedef unsigned short u16;
typedef __attribute__((ext_vector_type(8))) short v8s;   // 8 bf16 (4 VGPRs)
typedef __attribute__((ext_vector_type(4))) float v4f;

static __device__ __forceinline__ float bf2f(u16 u) {
  union { unsigned u; float f; } c;
  c.u = (unsigned)u << 16;
  return c.f;
}
static __device__ __forceinline__ u16 f2bf(float f) {
  union { float f; unsigned u; } c;
  c.f = f;
  unsigned r = c.u + 0x7fff + ((c.u >> 16) & 1);   // RNE
  return (u16)(r >> 16);
}
static __device__ __forceinline__ long ld_idx(const void* p, long i, int is64) {
  return is64 ? (long)((const long long*)p)[i] : (long)((const int*)p)[i];
}
static __device__ __forceinline__ float ld_f(const int* flags, const void* p, long i) {
  return flags[0] ? ((const float*)p)[i] : bf2f(((const u16*)p)[i]);
}

// flags[0]=fp32 floats; flags[1]=entity i64; flags[2]=edge_index i64; flags[3]=edge_type i64
__global__ __launch_bounds__(256) void detect_kernel(
    const u16* __restrict__ table, const void* __restrict__ entity,
    const void* __restrict__ ei, const void* __restrict__ et,
    int* __restrict__ flags) {
  __shared__ int s_f, s_ei, s_et;
  if (threadIdx.x == 0) { s_f = 0; s_ei = 0; s_et = 0; }
  __syncthreads();
  int cf = 0, cei = 0, cet = 0;
  for (int i = threadIdx.x; i < 65536; i += 256) {
    u16 u = table[i];
    if (((u >> 7) & 0xFF) == 0xFF) cf++;
  }
  const int* ei32 = (const int*)ei;
  const int* et32 = (const int*)et;
  for (int i = threadIdx.x; i < 1024; i += 256) {
    if (ei32[2 * i + 1] != 0) cei++;
    if (et32[2 * i + 1] != 0) cet++;
  }
  if (cf) atomicAdd(&s_f, cf);
  if (cei) atomicAdd(&s_ei, cei);
  if (cet) atomicAdd(&s_et, cet);
  __syncthreads();
  if (threadIdx.x == 0) {
    flags[0] = (s_f > 0) ? 1 : 0;
    flags[1] = (((const int*)entity)[1] == 0) ? 1 : 0;
    flags[2] = (s_ei == 0) ? 1 : 0;
    flags[3] = (s_et == 0) ? 1 : 0;
  }
}

__global__ __launch_bounds__(256) void conv_kernel(const int* __restrict__ flags,
                                                   const void* __restrict__ src,
                                                   float* __restrict__ dst, int n) {
  int i = blockIdx.x * 256 + threadIdx.x;
  if (i < n) dst[i] = ld_f(flags, src, i);
}

// Wcat[k][640] = [basis0..3 | root], fp32 (root slice feeds the fp32 root GEMM)
__global__ __launch_bounds__(256) void wcat_kernel(const int* __restrict__ flags,
                                                   const void* __restrict__ basis,
                                                   const void* __restrict__ root,
                                                   float* __restrict__ Wcat) {
  int i = blockIdx.x * 256 + threadIdx.x;
  if (i >= 128 * 640) return;
  int k = i / 640, c = i % 640;
  const void* src;
  long si;
  if (c < 512) { src = basis; si = (long)(c >> 7) * DIM * DIM + k * DIM + (c & 127); }
  else         { src = root;  si = (long)k * DIM + (c - 512); }
  Wcat[i] = ld_f(flags, src, si);
}

// Wt[512][128] bf16 = transposed bases: Wt[b*128+c][k] = basis[b][k][c]
__global__ __launch_bounds__(256) void wtbf_kernel(const int* __restrict__ flags,
                                                   const void* __restrict__ basis,
                                                   u16* __restrict__ Wt) {
  int i = blockIdx.x * 256 + threadIdx.x;
  if (i >= 512 * 128) return;
  int n = i >> 7, k = i & 127;
  int b = n >> 7, c = n & 127;
  Wt[i] = f2bf(ld_f(flags, basis, (long)b * DIM * DIM + (long)k * DIM + c));
}

// h fp32 (d_out) + hbf bf16 (ws) = table[entity[row]]
__global__ __launch_bounds__(256) void gather_kernel(const int* __restrict__ flags,
                                                     const void* __restrict__ entity,
                                                     const void* __restrict__ table,
                                                     float* __restrict__ h,
                                                     u16* __restrict__ hbf) {
  int gid = blockIdx.x * 256 + threadIdx.x;      // N*32 threads, 4 elems each
  int row = gid >> 5, c4 = (gid & 31) * 4;
  if (row >= NROWS) return;
  long src = ld_idx(entity, row, flags[1]);
  float4 o;
  if (flags[0]) {
    o = *(const float4*)((const float*)table + src * DIM + c4);
  } else {
    ushort4 a = *(const ushort4*)((const u16*)table + src * DIM + c4);
    o = make_float4(bf2f(a.x), bf2f(a.y), bf2f(a.z), bf2f(a.w));
  }
  *(float4*)(h + (long)row * DIM + c4) = o;
  *(ushort4*)(hbf + (long)row * DIM + c4) =
      make_ushort4(f2bf(o.x), f2bf(o.y), f2bf(o.z), f2bf(o.w));
}

// -------- CSR build -------------------------------------------------------------
__global__ __launch_bounds__(256) void hist_kernel(const int* __restrict__ flags,
                                                   const void* __restrict__ ei,
                                                   int* __restrict__ cnt) {
  int e = blockIdx.x * 256 + threadIdx.x;
  if (e < EDGES) atomicAdd(cnt + ld_idx(ei, EDGES + e, flags[2]), 1);
}

// hierarchical scan, phase 1: per-block exclusive scan + block sums
__global__ __launch_bounds__(256) void scan1_kernel(const int* __restrict__ cnt,
                                                    int* __restrict__ rowPtr,
                                                    int* __restrict__ bsum) {
  __shared__ int sh[256];
  int i = blockIdx.x * 256 + threadIdx.x;
  int v = (i < NROWS) ? cnt[i] : 0;
  sh[threadIdx.x] = v;
  __syncthreads();
#pragma unroll
  for (int off = 1; off < 256; off <<= 1) {
    int t = (threadIdx.x >= off) ? sh[threadIdx.x - off] : 0;
    __syncthreads();
    sh[threadIdx.x] += t;
    __syncthreads();
  }
  if (i < NROWS) rowPtr[i] = sh[threadIdx.x] - v;   // block-local exclusive
  if (threadIdx.x == 255) bsum[blockIdx.x] = sh[255];
}

// phase 2: single small block scans the 391 block sums -> exclusive offsets
__global__ __launch_bounds__(512) void scan2_kernel(int* __restrict__ bsum,
                                                    int* __restrict__ bofs,
                                                    int* __restrict__ rowPtr) {
  __shared__ int sh[512];
  int v = (threadIdx.x < SCAN_B) ? bsum[threadIdx.x] : 0;
  sh[threadIdx.x] = v;
  __syncthreads();
#pragma unroll
  for (int off = 1; off < 512; off <<= 1) {
    int t = (threadIdx.x >= off) ? sh[threadIdx.x - off] : 0;
    __syncthreads();
    sh[threadIdx.x] += t;
    __syncthreads();
  }
  if (threadIdx.x < SCAN_B) bofs[threadIdx.x] = sh[threadIdx.x] - v;
  if (threadIdx.x == 511) rowPtr[NROWS] = sh[511];   // total = EDGES
}

// phase 3: add block offsets; also init cursor (replaces d2d memcpy)
__global__ __launch_bounds__(256) void scan3_kernel(int* __restrict__ rowPtr,
                                                    const int* __restrict__ bofs,
                                                    int* __restrict__ cursor) {
  int i = blockIdx.x * 256 + threadIdx.x;
  if (i >= NROWS) return;
  int r = rowPtr[i] + bofs[blockIdx.x];
  rowPtr[i] = r;
  cursor[i] = r;
}

__global__ __launch_bounds__(256) void scatter_kernel(const int* __restrict__ flags,
                                                      const void* __restrict__ ei,
                                                      const void* __restrict__ et,
                                                      const void* __restrict__ enorm,
                                                      int* __restrict__ cursor,
                                                      int* __restrict__ csr_packed,
                                                      float* __restrict__ csr_norm) {
  int e = blockIdx.x * 256 + threadIdx.x;
  if (e >= EDGES) return;
  int dst = (int)ld_idx(ei, EDGES + e, flags[2]);
  int src = (int)ld_idx(ei, e, flags[2]);
  int t = (int)ld_idx(et, e, flags[3]);
  int pos = atomicAdd(cursor + dst, 1);
  csr_packed[pos] = src | (t << 17);
  csr_norm[pos] = ld_f(flags, enorm, e);
}

// -------- fp32 GEMM (root path only: by>=nYtiles=0): acc = h@root + bias --------
__global__ __launch_bounds__(256) void gemm_kernel(
    const float* __restrict__ h, const float* __restrict__ Wcat,
    const float* __restrict__ bias, u16* __restrict__ Y,
    void* __restrict__ acc, int accF32, int rowBase, int rowEnd, int nYtiles) {
  __shared__ float As[64][132];
  __shared__ float Ws[64][68];
  int by = blockIdx.y;
  int isRoot = (by >= nYtiles);
  int gcol = isRoot ? (512 + (by - nYtiles) * 64) : (by * 64);
  long m0 = rowBase + (long)blockIdx.x * 128;
  int tx = threadIdx.x & 15, ty = threadIdx.x >> 4;
  float av[8][4] = {};

  for (int k0 = 0; k0 < 128; k0 += 64) {
#pragma unroll
    for (int it = 0; it < 8; ++it) {
      int lin = threadIdx.x + it * 256;
      int row = lin >> 4, c4 = (lin & 15) * 4;
      long grow = m0 + row;
      float4 v = make_float4(0.f, 0.f, 0.f, 0.f);
      if (grow < rowEnd) v = *(const float4*)&h[grow * DIM + k0 + c4];
      As[c4 + 0][row] = v.x;
      As[c4 + 1][row] = v.y;
      As[c4 + 2][row] = v.z;
      As[c4 + 3][row] = v.w;
    }
#pragma unroll
    for (int it = 0; it < 4; ++it) {
      int lin = threadIdx.x + it * 256;
      int k = lin >> 4, n4 = lin & 15;
      *(float4*)&Ws[k][n4 * 4] = *(const float4*)&Wcat[(long)(k0 + k) * 640 + gcol + n4 * 4];
    }
    __syncthreads();
#pragma unroll
    for (int k = 0; k < 64; ++k) {
      float a[8], b[4];
      *(float4*)&a[0] = *(const float4*)&As[k][ty * 8];
      *(float4*)&a[4] = *(const float4*)&As[k][ty * 8 + 4];
      *(float4*)&b[0] = *(const float4*)&Ws[k][tx * 4];
#pragma unroll
      for (int i = 0; i < 8; ++i)
#pragma unroll
        for (int j = 0; j < 4; ++j) av[i][j] = fmaf(a[i], b[j], av[i][j]);
    }
    __syncthreads();
  }

#pragma unroll
  for (int i = 0; i < 8; ++i) {
    long row = m0 + ty * 8 + i;
    if (row >= rowEnd) continue;
    if (isRoot) {
      int c = gcol - 512 + tx * 4;
      float o0 = av[i][0] + bias[c], o1 = av[i][1] + bias[c + 1];
      float o2 = av[i][2] + bias[c + 2], o3 = av[i][3] + bias[c + 3];
      if (accF32) {
        *(float4*)&((float*)acc)[row * DIM + c] = make_float4(o0, o1, o2, o3);
      } else {
        *(ushort4*)&((u16*)acc)[row * DIM + c] =
            make_ushort4(f2bf(o0), f2bf(o1), f2bf(o2), f2bf(o3));
      }
    } else {
      *(ushort4*)&Y[(row - rowBase) * 512 + gcol + tx * 4] =
          make_ushort4(f2bf(av[i][0]), f2bf(av[i][1]), f2bf(av[i][2]), f2bf(av[i][3]));
    }
  }
}

// -------- MFMA bf16 GEMM: Y[chunk rows][512] = hbf @ bases ----------------------
__global__ __launch_bounds__(256) void mgemm_kernel(
    const u16* __restrict__ hbf, const u16* __restrict__ Wt,   // Wt[512][128] bf16
    u16* __restrict__ Y, int rowBase, int rowEnd) {
  __shared__ u16 Wl[128 * 136];
  int nb = blockIdx.y * 128;
#pragma unroll
  for (int it = 0; it < 8; ++it) {
    int idx = threadIdx.x + it * 256;
    int n = idx >> 4, kk = (idx & 15) * 8;
    *(int4*)&Wl[n * 136 + kk] = *(const int4*)&Wt[(long)(nb + n) * 128 + kk];
  }
  __syncthreads();

  int wave = threadIdx.x >> 6, lane = threadIdx.x & 63;
  int quad = lane >> 4, l16 = lane & 15;
  long arow = rowBase + (long)blockIdx.x * 64 + wave * 16 + l16;
  bool rv = arow < rowEnd;

  v4f acc[8];
#pragma unroll
  for (int nt = 0; nt < 8; ++nt) acc[nt] = (v4f){0.f, 0.f, 0.f, 0.f};

#pragma unroll
  for (int ks = 0; ks < 4; ++ks) {
    int k0 = ks * 32;
    v8s a = {0, 0, 0, 0, 0, 0, 0, 0};
    if (rv) a = *(const v8s*)&hbf[arow * DIM + k0 + quad * 8];
#pragma unroll
    for (int nt = 0; nt < 8; ++nt) {
      v8s b = *(const v8s*)&Wl[(nt * 16 + l16) * 136 + k0 + quad * 8];
      acc[nt] = __builtin_amdgcn_mfma_f32_16x16x32_bf16(a, b, acc[nt], 0, 0, 0);
    }
  }

  long lrow0 = (long)blockIdx.x * 64 + wave * 16 + quad * 4;   // chunk-local
#pragma unroll
  for (int nt = 0; nt < 8; ++nt) {
#pragma unroll
    for (int r = 0; r < 4; ++r) {
      long lrow = lrow0 + r;
      if (rowBase + lrow < rowEnd)
        Y[lrow * 512 + nb + nt * 16 + l16] = f2bf(acc[nt][r]);
    }
  }
}

// -------- CSR aggregation, one wave/node, src filtered to [c0,c1) ---------------
__global__ __launch_bounds__(256) void agg_kernel(
    const int* __restrict__ rowPtr, const int* __restrict__ csr_packed,
    const float* __restrict__ csr_norm, const float* __restrict__ att_f,
    const u16* __restrict__ Y, int c0, int c1,
    void* __restrict__ acc, int accF32, int finalMode,
    float* __restrict__ outp, u16* __restrict__ hbfOut) {
  int wid = (blockIdx.x * 256 + threadIdx.x) >> 6;
  int lane = threadIdx.x & 63;
  if (wid >= NROWS) return;
  int beg = rowPtr[wid], end = rowPtr[wid + 1];
  int d = lane * 2;
  float m0 = 0.f, m1 = 0.f;
  for (int e = beg; e < end; ++e) {
    int pk = csr_packed[e];
    int src = pk & 0x1FFFF;
    if ((unsigned)(src - c0) >= (unsigned)(c1 - c0)) continue;
    int t = pk >> 17;
    float nrm = csr_norm[e];
    const u16* y = Y + (long)(src - c0) * 512;
    float w[4];
#pragma unroll
    for (int b = 0; b < 4; ++b) w[b] = att_f[t * 4 + b] * nrm;
#pragma unroll
    for (int b = 0; b < 4; ++b) {
      unsigned v = *(const unsigned*)(y + b * DIM + d);
      m0 += w[b] * bf2f((u16)(v & 0xffffu));
      m1 += w[b] * bf2f((u16)(v >> 16));
    }
  }
  float invd = 1.0f / fmaxf((float)(end - beg), 1.0f);
  m0 *= invd; m1 *= invd;
  long o = (long)wid * DIM + d;
  if (finalMode == 0) {
    if (accF32) {
      ((float*)acc)[o] += m0;
      ((float*)acc)[o + 1] += m1;
    } else {
      u16* a = (u16*)acc;
      a[o] = f2bf(bf2f(a[o]) + m0);
      a[o + 1] = f2bf(bf2f(a[o + 1]) + m1);
    }
  } else {
    float a0, a1;
    if (accF32) { a0 = ((float*)acc)[o]; a1 = ((float*)acc)[o + 1]; }
    else        { a0 = bf2f(((u16*)acc)[o]); a1 = bf2f(((u16*)acc)[o + 1]); }
    float v0 = a0 + m0, v1 = a1 + m1;
    if (finalMode == 1) {
      v0 = fmaxf(v0, 0.f); v1 = fmaxf(v1, 0.f);
      outp[o] = v0;
      outp[o + 1] = v1;
      hbfOut[o] = f2bf(v0);
      hbfOut[o + 1] = f2bf(v1);
    } else {
      outp[o] = v0;
      outp[o + 1] = v1;
    }
  }
}

__global__ __launch_bounds__(256) void relout_kernel(const int* __restrict__ flags,
                                                     const void* __restrict__ rel,
                                                     float* __restrict__ out) {
  int i = blockIdx.x * 256 + threadIdx.x;
  if (i < 500 * DIM) out[i] = ld_f(flags, rel, i);
}

static size_t alignup(size_t x) { return (x + 255) & ~(size_t)255; }

extern "C" void kernel_launch(void* const* d_in, const int* in_sizes, int n_in,
                              void* d_out, int out_size, void* d_ws, size_t ws_size,
                              hipStream_t stream) {
  static const long exp_sz[15] = {100000, 1200000, 600000, 600000, 250000,
                                  12800000, 64000, 65536, 4000, 16384, 128,
                                  65536, 4000, 16384, 128};
  int map[15];
  bool posOK = (n_in >= 15);
  for (int i = 0; posOK && i < 15; ++i) posOK = (in_sizes[i] == exp_sz[i]);
  if (posOK) {
    for (int i = 0; i < 15; ++i) map[i] = i;
  } else {
    bool used[64] = {};
    for (int i = 0; i < 15; ++i) {
      map[i] = -1;
      for (int j = 0; j < n_in && j < 64; ++j)
        if (!used[j] && in_sizes[j] == exp_sz[i]) { map[i] = j; used[j] = true; break; }
      if (map[i] < 0) map[i] = (i < n_in) ? i : 0;
    }
  }
  const void* entity = d_in[map[0]];
  const void* edge_index = d_in[map[1]];
  const void* edge_type = d_in[map[2]];
  const void* edge_norm = d_in[map[3]];
  const void* table = d_in[map[5]];
  const void* rel_emb = d_in[map[6]];
  const void* basis[2] = {d_in[map[7]], d_in[map[11]]};
  const void* att[2] = {d_in[map[8]], d_in[map[12]]};
  const void* root[2] = {d_in[map[9]], d_in[map[13]]};
  const void* bias[2] = {d_in[map[10]], d_in[map[14]]};

  // ---- fixed ws layout (~32.5 MB incl. hbf) ----
  char* ws = (char*)d_ws;
  size_t off = 0;
  auto grab = [&](size_t bytes) { size_t o = off; off = alignup(off + bytes); return o; };
  int* flags = (int*)(ws + grab(16));
  float* att_f[2] = {(float*)(ws + grab(4000 * 4)), (float*)(ws + grab(4000 * 4))};
  float* bias_f[2] = {(float*)(ws + grab(DIM * 4)), (float*)(ws + grab(DIM * 4))};
  float* Wcat[2] = {(float*)(ws + grab(128 * 640 * 4)), (float*)(ws + grab(128 * 640 * 4))};
  u16* Wt[2] = {(u16*)(ws + grab(512 * 128 * 2)), (u16*)(ws + grab(512 * 128 * 2))};
  int* cnt = (int*)(ws + grab((size_t)NROWS * 4));
  int* cursor = (int*)(ws + grab((size_t)NROWS * 4));
  int* rowPtr = (int*)(ws + grab((size_t)(NROWS + 1) * 4));
  int* bsum = (int*)(ws + grab((size_t)SCAN_B * 4));
  int* bofs = (int*)(ws + grab((size_t)SCAN_B * 4));
  int* csr_packed = (int*)(ws + grab((size_t)EDGES * 4));
  float* csr_norm = (float*)(ws + grab((size_t)EDGES * 4));
  u16* hbf = (u16*)(ws + grab((size_t)NROWS * DIM * 2));
  size_t fixedB = off;

  // ---- pick (node-chunks NC, acc precision) that fits ws_size ----
  const size_t accF32B = (size_t)NROWS * DIM * 4, accBF16B = (size_t)NROWS * DIM * 2;
  static const int ncOrd[10] = {1, 2, 4, 8, 16, 1, 2, 4, 8, 16};
  static const int f32Ord[10] = {1, 1, 1, 1, 1, 0, 0, 0, 0, 0};
  int NC = 16, accF32 = 0;
  for (int i = 0; i < 10; ++i) {
    int nc = ncOrd[i];
    size_t r = (NROWS + nc - 1) / nc;
    size_t need = fixedB + (f32Ord[i] ? accF32B : accBF16B) + r * 512 * 2;
    if (need <= ws_size) { NC = nc; accF32 = f32Ord[i]; break; }
  }
  void* acc = (void*)(ws + grab(accF32 ? accF32B : accBF16B));
  const int rpc = (NROWS + NC - 1) / NC;
  u16* Y = (u16*)(ws + grab((size_t)rpc * 512 * 2));
  float* h = (float*)d_out;   // fp32 node features live in the output region

  // ---- prep ----
  detect_kernel<<<1, 256, 0, stream>>>((const u16*)table, entity, edge_index,
                                       edge_type, flags);
  for (int l = 0; l < 2; ++l) {
    wcat_kernel<<<320, 256, 0, stream>>>(flags, basis[l], root[l], Wcat[l]);
    wtbf_kernel<<<256, 256, 0, stream>>>(flags, basis[l], Wt[l]);
    conv_kernel<<<16, 256, 0, stream>>>(flags, att[l], att_f[l], 4000);
    conv_kernel<<<1, 256, 0, stream>>>(flags, bias[l], bias_f[l], DIM);
  }
  gather_kernel<<<(NROWS * 32 + 255) / 256, 256, 0, stream>>>(flags, entity, table, h, hbf);
  hipMemsetAsync(cnt, 0, (size_t)NROWS * 4, stream);
  hist_kernel<<<(EDGES + 255) / 256, 256, 0, stream>>>(flags, edge_index, cnt);
  scan1_kernel<<<SCAN_B, 256, 0, stream>>>(cnt, rowPtr, bsum);
  scan2_kernel<<<1, 512, 0, stream>>>(bsum, bofs, rowPtr);
  scan3_kernel<<<SCAN_B, 256, 0, stream>>>(rowPtr, bofs, cursor);
  scatter_kernel<<<(EDGES + 255) / 256, 256, 0, stream>>>(
      flags, edge_index, edge_type, edge_norm, cursor, csr_packed, csr_norm);

  // ---- two RGCN layers ----
  const int aggBlocks = (NROWS * 64) / 256;           // 25000
  const int rootMt = (NROWS + 127) / 128;             // 782
  for (int l = 0; l < 2; ++l) {
    gemm_kernel<<<dim3(rootMt, 2), 256, 0, stream>>>(
        h, Wcat[l], bias_f[l], Y, acc, accF32, 0, NROWS, 0);
    for (int c = 0; c < NC; ++c) {
      int c0 = c * rpc, c1 = (c0 + rpc < NROWS) ? c0 + rpc : NROWS;
      int mt = (c1 - c0 + 63) / 64;
      mgemm_kernel<<<dim3(mt, 4), 256, 0, stream>>>(hbf, Wt[l], Y, c0, c1);
      int fm = (c == NC - 1) ? (l == 0 ? 1 : 2) : 0;
      agg_kernel<<<aggBlocks, 256, 0, stream>>>(
          rowPtr, csr_packed, csr_norm, att_f[l], Y, c0, c1, acc, accF32, fm, h, hbf);
    }
  }

  relout_kernel<<<250, 256, 0, stream>>>(flags, rel_emb, (float*)d_out + (size_t)NROWS * DIM);
}

// Round 9
// 610.584 us; speedup vs baseline: 2.0296x; 1.1684x over previous
//
#include <hip/hip_runtime.h>
#include <hip/hip_bf16.h>

#define NROWS 100000
#define EDGES 600000
#define DIM 128
#define SCAN_B 391   // ceil(100000/256)

typedef unsigned short u16;
typedef __attribute__((ext_vector_type(8))) short v8s;   // 8 bf16 (4 VGPRs)
typedef __attribute__((ext_vector_type(4))) float v4f;

static __device__ __forceinline__ float bf2f(u16 u) {
  union { unsigned u; float f; } c;
  c.u = (unsigned)u << 16;
  return c.f;
}
static __device__ __forceinline__ u16 f2bf(float f) {
  union { float f; unsigned u; } c;
  c.f = f;
  unsigned r = c.u + 0x7fff + ((c.u >> 16) & 1);   // RNE
  return (u16)(r >> 16);
}
static __device__ __forceinline__ long ld_idx(const void* p, long i, int is64) {
  return is64 ? (long)((const long long*)p)[i] : (long)((const int*)p)[i];
}
static __device__ __forceinline__ float ld_f(const int* flags, const void* p, long i) {
  return flags[0] ? ((const float*)p)[i] : bf2f(((const u16*)p)[i]);
}

// flags[0]=fp32 floats; flags[1]=entity i64; flags[2]=edge_index i64; flags[3]=edge_type i64
__global__ __launch_bounds__(256) void detect_kernel(
    const u16* __restrict__ table, const void* __restrict__ entity,
    const void* __restrict__ ei, const void* __restrict__ et,
    int* __restrict__ flags) {
  __shared__ int s_f, s_ei, s_et;
  if (threadIdx.x == 0) { s_f = 0; s_ei = 0; s_et = 0; }
  __syncthreads();
  int cf = 0, cei = 0, cet = 0;
  for (int i = threadIdx.x; i < 65536; i += 256) {
    u16 u = table[i];
    if (((u >> 7) & 0xFF) == 0xFF) cf++;
  }
  const int* ei32 = (const int*)ei;
  const int* et32 = (const int*)et;
  for (int i = threadIdx.x; i < 1024; i += 256) {
    if (ei32[2 * i + 1] != 0) cei++;
    if (et32[2 * i + 1] != 0) cet++;
  }
  if (cf) atomicAdd(&s_f, cf);
  if (cei) atomicAdd(&s_ei, cei);
  if (cet) atomicAdd(&s_et, cet);
  __syncthreads();
  if (threadIdx.x == 0) {
    flags[0] = (s_f > 0) ? 1 : 0;
    flags[1] = (((const int*)entity)[1] == 0) ? 1 : 0;
    flags[2] = (s_ei == 0) ? 1 : 0;
    flags[3] = (s_et == 0) ? 1 : 0;
  }
}

__global__ __launch_bounds__(256) void conv_kernel(const int* __restrict__ flags,
                                                   const void* __restrict__ src,
                                                   float* __restrict__ dst, int n) {
  int i = blockIdx.x * 256 + threadIdx.x;
  if (i < n) dst[i] = ld_f(flags, src, i);
}

// Wt[640][128] bf16: rows 0..511 = transposed bases (Wt[b*128+c][k]=basis[b][k][c]);
// rows 512..639 = transposed root (Wt[512+c][k]=root[k][c])
__global__ __launch_bounds__(256) void wtbf_kernel(const int* __restrict__ flags,
                                                   const void* __restrict__ basis,
                                                   const void* __restrict__ root,
                                                   u16* __restrict__ Wt) {
  int i = blockIdx.x * 256 + threadIdx.x;
  if (i >= 640 * 128) return;
  int n = i >> 7, k = i & 127;
  float v;
  if (n < 512) {
    int b = n >> 7, c = n & 127;
    v = ld_f(flags, basis, (long)b * DIM * DIM + (long)k * DIM + c);
  } else {
    v = ld_f(flags, root, (long)k * DIM + (n - 512));
  }
  Wt[i] = f2bf(v);
}

// hbf bf16 (ws) = table[entity[row]]
__global__ __launch_bounds__(256) void gather_kernel(const int* __restrict__ flags,
                                                     const void* __restrict__ entity,
                                                     const void* __restrict__ table,
                                                     u16* __restrict__ hbf) {
  int gid = blockIdx.x * 256 + threadIdx.x;      // N*32 threads, 4 elems each
  int row = gid >> 5, c4 = (gid & 31) * 4;
  if (row >= NROWS) return;
  long src = ld_idx(entity, row, flags[1]);
  ushort4 o;
  if (flags[0]) {
    float4 a = *(const float4*)((const float*)table + src * DIM + c4);
    o = make_ushort4(f2bf(a.x), f2bf(a.y), f2bf(a.z), f2bf(a.w));
  } else {
    o = *(const ushort4*)((const u16*)table + src * DIM + c4);
  }
  *(ushort4*)(hbf + (long)row * DIM + c4) = o;
}

// -------- CSR build -------------------------------------------------------------
__global__ __launch_bounds__(256) void hist_kernel(const int* __restrict__ flags,
                                                   const void* __restrict__ ei,
                                                   int* __restrict__ cnt) {
  int e = blockIdx.x * 256 + threadIdx.x;
  if (e < EDGES) atomicAdd(cnt + ld_idx(ei, EDGES + e, flags[2]), 1);
}

__global__ __launch_bounds__(256) void scan1_kernel(const int* __restrict__ cnt,
                                                    int* __restrict__ rowPtr,
                                                    int* __restrict__ bsum) {
  __shared__ int sh[256];
  int i = blockIdx.x * 256 + threadIdx.x;
  int v = (i < NROWS) ? cnt[i] : 0;
  sh[threadIdx.x] = v;
  __syncthreads();
#pragma unroll
  for (int off = 1; off < 256; off <<= 1) {
    int t = (threadIdx.x >= off) ? sh[threadIdx.x - off] : 0;
    __syncthreads();
    sh[threadIdx.x] += t;
    __syncthreads();
  }
  if (i < NROWS) rowPtr[i] = sh[threadIdx.x] - v;
  if (threadIdx.x == 255) bsum[blockIdx.x] = sh[255];
}

__global__ __launch_bounds__(512) void scan2_kernel(int* __restrict__ bsum,
                                                    int* __restrict__ bofs,
                                                    int* __restrict__ rowPtr) {
  __shared__ int sh[512];
  int v = (threadIdx.x < SCAN_B) ? bsum[threadIdx.x] : 0;
  sh[threadIdx.x] = v;
  __syncthreads();
#pragma unroll
  for (int off = 1; off < 512; off <<= 1) {
    int t = (threadIdx.x >= off) ? sh[threadIdx.x - off] : 0;
    __syncthreads();
    sh[threadIdx.x] += t;
    __syncthreads();
  }
  if (threadIdx.x < SCAN_B) bofs[threadIdx.x] = sh[threadIdx.x] - v;
  if (threadIdx.x == 511) rowPtr[NROWS] = sh[511];
}

__global__ __launch_bounds__(256) void scan3_kernel(int* __restrict__ rowPtr,
                                                    const int* __restrict__ bofs,
                                                    int* __restrict__ cursor) {
  int i = blockIdx.x * 256 + threadIdx.x;
  if (i >= NROWS) return;
  int r = rowPtr[i] + bofs[blockIdx.x];
  rowPtr[i] = r;
  cursor[i] = r;
}

__global__ __launch_bounds__(256) void scatter_kernel(const int* __restrict__ flags,
                                                      const void* __restrict__ ei,
                                                      const void* __restrict__ et,
                                                      const void* __restrict__ enorm,
                                                      int* __restrict__ cursor,
                                                      int* __restrict__ csr_packed,
                                                      float* __restrict__ csr_norm) {
  int e = blockIdx.x * 256 + threadIdx.x;
  if (e >= EDGES) return;
  int dst = (int)ld_idx(ei, EDGES + e, flags[2]);
  int src = (int)ld_idx(ei, e, flags[2]);
  int t = (int)ld_idx(et, e, flags[3]);
  int pos = atomicAdd(cursor + dst, 1);
  csr_packed[pos] = src | (t << 17);
  csr_norm[pos] = ld_f(flags, enorm, e);
}

// -------- MFMA bf16 GEMM: Y[chunk rows][512] = hbf @ bases ----------------------
__global__ __launch_bounds__(256) void mgemm_kernel(
    const u16* __restrict__ hbf, const u16* __restrict__ Wt,   // Wt[640][128] bf16
    u16* __restrict__ Y, int rowBase, int rowEnd) {
  __shared__ u16 Wl[128 * 136];
  int nb = blockIdx.y * 128;
#pragma unroll
  for (int it = 0; it < 8; ++it) {
    int idx = threadIdx.x + it * 256;
    int n = idx >> 4, kk = (idx & 15) * 8;
    *(int4*)&Wl[n * 136 + kk] = *(const int4*)&Wt[(long)(nb + n) * 128 + kk];
  }
  __syncthreads();

  int wave = threadIdx.x >> 6, lane = threadIdx.x & 63;
  int quad = lane >> 4, l16 = lane & 15;
  long arow = rowBase + (long)blockIdx.x * 64 + wave * 16 + l16;
  bool rv = arow < rowEnd;

  v4f acc[8];
#pragma unroll
  for (int nt = 0; nt < 8; ++nt) acc[nt] = (v4f){0.f, 0.f, 0.f, 0.f};

#pragma unroll
  for (int ks = 0; ks < 4; ++ks) {
    int k0 = ks * 32;
    v8s a = {0, 0, 0, 0, 0, 0, 0, 0};
    if (rv) a = *(const v8s*)&hbf[arow * DIM + k0 + quad * 8];
#pragma unroll
    for (int nt = 0; nt < 8; ++nt) {
      v8s b = *(const v8s*)&Wl[(nt * 16 + l16) * 136 + k0 + quad * 8];
      acc[nt] = __builtin_amdgcn_mfma_f32_16x16x32_bf16(a, b, acc[nt], 0, 0, 0);
    }
  }

  long lrow0 = (long)blockIdx.x * 64 + wave * 16 + quad * 4;   // chunk-local
#pragma unroll
  for (int nt = 0; nt < 8; ++nt) {
#pragma unroll
    for (int r = 0; r < 4; ++r) {
      long lrow = lrow0 + r;
      if (rowBase + lrow < rowEnd)
        Y[lrow * 512 + nb + nt * 16 + l16] = f2bf(acc[nt][r]);
    }
  }
}

// -------- MFMA root GEMM: acc[row][128] = hbf @ root + bias (fp32 or bf16) ------
__global__ __launch_bounds__(256) void rgemm_kernel(
    const u16* __restrict__ hbf, const u16* __restrict__ Wt,
    const float* __restrict__ bias, void* __restrict__ acc, int accF32) {
  __shared__ u16 Wl[128 * 136];
#pragma unroll
  for (int it = 0; it < 8; ++it) {
    int idx = threadIdx.x + it * 256;
    int n = idx >> 4, kk = (idx & 15) * 8;
    *(int4*)&Wl[n * 136 + kk] = *(const int4*)&Wt[(long)(512 + n) * 128 + kk];
  }
  __syncthreads();

  int wave = threadIdx.x >> 6, lane = threadIdx.x & 63;
  int quad = lane >> 4, l16 = lane & 15;
  long arow = (long)blockIdx.x * 64 + wave * 16 + l16;
  bool rv = arow < NROWS;

  v4f av[8];
#pragma unroll
  for (int nt = 0; nt < 8; ++nt) av[nt] = (v4f){0.f, 0.f, 0.f, 0.f};

#pragma unroll
  for (int ks = 0; ks < 4; ++ks) {
    int k0 = ks * 32;
    v8s a = {0, 0, 0, 0, 0, 0, 0, 0};
    if (rv) a = *(const v8s*)&hbf[arow * DIM + k0 + quad * 8];
#pragma unroll
    for (int nt = 0; nt < 8; ++nt) {
      v8s b = *(const v8s*)&Wl[(nt * 16 + l16) * 136 + k0 + quad * 8];
      av[nt] = __builtin_amdgcn_mfma_f32_16x16x32_bf16(a, b, av[nt], 0, 0, 0);
    }
  }

  long row0 = (long)blockIdx.x * 64 + wave * 16 + quad * 4;
#pragma unroll
  for (int nt = 0; nt < 8; ++nt) {
    int col = nt * 16 + l16;
    float bv = bias[col];
#pragma unroll
    for (int r = 0; r < 4; ++r) {
      long row = row0 + r;
      if (row >= NROWS) continue;
      float v = av[nt][r] + bv;
      if (accF32) ((float*)acc)[row * DIM + col] = v;
      else        ((u16*)acc)[row * DIM + col] = f2bf(v);
    }
  }
}

// -------- CSR aggregation, one wave/node, src filtered to [c0,c1) ---------------
// finalMode 0: acc += msg/deg | 1: hbf = bf16(relu(acc+msg/deg)) | 2: outp fp32
__global__ __launch_bounds__(256) void agg_kernel(
    const int* __restrict__ rowPtr, const int* __restrict__ csr_packed,
    const float* __restrict__ csr_norm, const float* __restrict__ att_f,
    const u16* __restrict__ Y, int c0, int c1,
    void* __restrict__ acc, int accF32, int finalMode,
    float* __restrict__ outp, u16* __restrict__ hbfOut) {
  int wid = (blockIdx.x * 256 + threadIdx.x) >> 6;
  int lane = threadIdx.x & 63;
  if (wid >= NROWS) return;
  int beg = rowPtr[wid], end = rowPtr[wid + 1];
  int d = lane * 2;
  float m0 = 0.f, m1 = 0.f;
  for (int e = beg; e < end; ++e) {
    int pk = csr_packed[e];
    int src = pk & 0x1FFFF;
    if ((unsigned)(src - c0) >= (unsigned)(c1 - c0)) continue;
    int t = pk >> 17;
    float nrm = csr_norm[e];
    const u16* y = Y + (long)(src - c0) * 512;
    float w[4];
#pragma unroll
    for (int b = 0; b < 4; ++b) w[b] = att_f[t * 4 + b] * nrm;
#pragma unroll
    for (int b = 0; b < 4; ++b) {
      unsigned v = *(const unsigned*)(y + b * DIM + d);
      m0 += w[b] * bf2f((u16)(v & 0xffffu));
      m1 += w[b] * bf2f((u16)(v >> 16));
    }
  }
  float invd = 1.0f / fmaxf((float)(end - beg), 1.0f);
  m0 *= invd; m1 *= invd;
  long o = (long)wid * DIM + d;
  if (finalMode == 0) {
    if (accF32) {
      ((float*)acc)[o] += m0;
      ((float*)acc)[o + 1] += m1;
    } else {
      u16* a = (u16*)acc;
      a[o] = f2bf(bf2f(a[o]) + m0);
      a[o + 1] = f2bf(bf2f(a[o + 1]) + m1);
    }
  } else {
    float a0, a1;
    if (accF32) { a0 = ((float*)acc)[o]; a1 = ((float*)acc)[o + 1]; }
    else        { a0 = bf2f(((u16*)acc)[o]); a1 = bf2f(((u16*)acc)[o + 1]); }
    float v0 = a0 + m0, v1 = a1 + m1;
    if (finalMode == 1) {
      hbfOut[o] = f2bf(fmaxf(v0, 0.f));
      hbfOut[o + 1] = f2bf(fmaxf(v1, 0.f));
    } else {
      outp[o] = v0;
      outp[o + 1] = v1;
    }
  }
}

__global__ __launch_bounds__(256) void relout_kernel(const int* __restrict__ flags,
                                                     const void* __restrict__ rel,
                                                     float* __restrict__ out) {
  int i = blockIdx.x * 256 + threadIdx.x;
  if (i < 500 * DIM) out[i] = ld_f(flags, rel, i);
}

static size_t alignup(size_t x) { return (x + 255) & ~(size_t)255; }

extern "C" void kernel_launch(void* const* d_in, const int* in_sizes, int n_in,
                              void* d_out, int out_size, void* d_ws, size_t ws_size,
                              hipStream_t stream) {
  static const long exp_sz[15] = {100000, 1200000, 600000, 600000, 250000,
                                  12800000, 64000, 65536, 4000, 16384, 128,
                                  65536, 4000, 16384, 128};
  int map[15];
  bool posOK = (n_in >= 15);
  for (int i = 0; posOK && i < 15; ++i) posOK = (in_sizes[i] == exp_sz[i]);
  if (posOK) {
    for (int i = 0; i < 15; ++i) map[i] = i;
  } else {
    bool used[64] = {};
    for (int i = 0; i < 15; ++i) {
      map[i] = -1;
      for (int j = 0; j < n_in && j < 64; ++j)
        if (!used[j] && in_sizes[j] == exp_sz[i]) { map[i] = j; used[j] = true; break; }
      if (map[i] < 0) map[i] = (i < n_in) ? i : 0;
    }
  }
  const void* entity = d_in[map[0]];
  const void* edge_index = d_in[map[1]];
  const void* edge_type = d_in[map[2]];
  const void* edge_norm = d_in[map[3]];
  const void* table = d_in[map[5]];
  const void* rel_emb = d_in[map[6]];
  const void* basis[2] = {d_in[map[7]], d_in[map[11]]};
  const void* att[2] = {d_in[map[8]], d_in[map[12]]};
  const void* root[2] = {d_in[map[9]], d_in[map[13]]};
  const void* bias[2] = {d_in[map[10]], d_in[map[14]]};

  // ---- fixed ws layout (~31 MB incl. hbf) ----
  char* ws = (char*)d_ws;
  size_t off = 0;
  auto grab = [&](size_t bytes) { size_t o = off; off = alignup(off + bytes); return o; };
  int* flags = (int*)(ws + grab(16));
  float* att_f[2] = {(float*)(ws + grab(4000 * 4)), (float*)(ws + grab(4000 * 4))};
  float* bias_f[2] = {(float*)(ws + grab(DIM * 4)), (float*)(ws + grab(DIM * 4))};
  u16* Wt[2] = {(u16*)(ws + grab(640 * 128 * 2)), (u16*)(ws + grab(640 * 128 * 2))};
  int* cnt = (int*)(ws + grab((size_t)NROWS * 4));
  int* cursor = (int*)(ws + grab((size_t)NROWS * 4));
  int* rowPtr = (int*)(ws + grab((size_t)(NROWS + 1) * 4));
  int* bsum = (int*)(ws + grab((size_t)SCAN_B * 4));
  int* bofs = (int*)(ws + grab((size_t)SCAN_B * 4));
  int* csr_packed = (int*)(ws + grab((size_t)EDGES * 4));
  float* csr_norm = (float*)(ws + grab((size_t)EDGES * 4));
  u16* hbf = (u16*)(ws + grab((size_t)NROWS * DIM * 2));
  size_t fixedB = off;

  // ---- pick (node-chunks NC, acc precision) that fits ws_size ----
  const size_t accF32B = (size_t)NROWS * DIM * 4, accBF16B = (size_t)NROWS * DIM * 2;
  static const int ncOrd[10] = {1, 2, 4, 8, 16, 1, 2, 4, 8, 16};
  static const int f32Ord[10] = {1, 1, 1, 1, 1, 0, 0, 0, 0, 0};
  int NC = 16, accF32 = 0;
  for (int i = 0; i < 10; ++i) {
    int nc = ncOrd[i];
    size_t r = (NROWS + nc - 1) / nc;
    size_t need = fixedB + (f32Ord[i] ? accF32B : accBF16B) + r * 512 * 2;
    if (need <= ws_size) { NC = nc; accF32 = f32Ord[i]; break; }
  }
  void* acc = (void*)(ws + grab(accF32 ? accF32B : accBF16B));
  const int rpc = (NROWS + NC - 1) / NC;
  u16* Y = (u16*)(ws + grab((size_t)rpc * 512 * 2));

  // ---- prep ----
  detect_kernel<<<1, 256, 0, stream>>>((const u16*)table, entity, edge_index,
                                       edge_type, flags);
  for (int l = 0; l < 2; ++l) {
    wtbf_kernel<<<320, 256, 0, stream>>>(flags, basis[l], root[l], Wt[l]);
    conv_kernel<<<16, 256, 0, stream>>>(flags, att[l], att_f[l], 4000);
    conv_kernel<<<1, 256, 0, stream>>>(flags, bias[l], bias_f[l], DIM);
  }
  gather_kernel<<<(NROWS * 32 + 255) / 256, 256, 0, stream>>>(flags, entity, table, hbf);
  hipMemsetAsync(cnt, 0, (size_t)NROWS * 4, stream);
  hist_kernel<<<(EDGES + 255) / 256, 256, 0, stream>>>(flags, edge_index, cnt);
  scan1_kernel<<<SCAN_B, 256, 0, stream>>>(cnt, rowPtr, bsum);
  scan2_kernel<<<1, 512, 0, stream>>>(bsum, bofs, rowPtr);
  scan3_kernel<<<SCAN_B, 256, 0, stream>>>(rowPtr, bofs, cursor);
  scatter_kernel<<<(EDGES + 255) / 256, 256, 0, stream>>>(
      flags, edge_index, edge_type, edge_norm, cursor, csr_packed, csr_norm);

  // ---- two RGCN layers ----
  const int aggBlocks = (NROWS * 64) / 256;           // 25000
  const int rootMt = (NROWS + 63) / 64;               // 1563
  for (int l = 0; l < 2; ++l) {
    rgemm_kernel<<<rootMt, 256, 0, stream>>>(hbf, Wt[l], bias_f[l], acc, accF32);
    for (int c = 0; c < NC; ++c) {
      int c0 = c * rpc, c1 = (c0 + rpc < NROWS) ? c0 + rpc : NROWS;
      int mt = (c1 - c0 + 63) / 64;
      mgemm_kernel<<<dim3(mt, 4), 256, 0, stream>>>(hbf, Wt[l], Y, c0, c1);
      int fm = (c == NC - 1) ? (l == 0 ? 1 : 2) : 0;
      agg_kernel<<<aggBlocks, 256, 0, stream>>>(
          rowPtr, csr_packed, csr_norm, att_f[l], Y, c0, c1, acc, accF32, fm,
          (float*)d_out, hbf);
    }
  }

  relout_kernel<<<250, 256, 0, stream>>>(flags, rel_emb, (float*)d_out + (size_t)NROWS * DIM);
}